// Round 1
// baseline (9666.116 us; speedup 1.0000x reference)
//
#include <hip/hip_runtime.h>
#include <hip/hip_cooperative_groups.h>
#include <stdint.h>

namespace cg = cooperative_groups;

typedef unsigned short u16;
typedef __bf16 bf16_t;
typedef bf16_t bf16x8 __attribute__((ext_vector_type(8)));
typedef float f32x4 __attribute__((ext_vector_type(4)));

#define Bdim 64
#define Tdim 256
#define Ddim 512
#define Hdim 1024
#define NGdim 4096

// ---------- helpers ----------
__device__ __forceinline__ u16 f2bf(float f) {
  union { float f; uint32_t u; } v; v.f = f;
  return (u16)((v.u + 0x7FFFu + ((v.u >> 16) & 1u)) >> 16);   // RNE
}
__device__ __forceinline__ float bf2f(u16 h) {
  union { uint32_t u; float f; } v; v.u = ((uint32_t)h) << 16;
  return v.f;
}
__device__ __forceinline__ float sigm(float x) { return 1.0f / (1.0f + __expf(-x)); }
__device__ __forceinline__ float tanh_fast(float x) { return 2.0f / (1.0f + __expf(-2.0f * x)) - 1.0f; }

__device__ __forceinline__ void load_lds16(const void* g, void* l) {
  __builtin_amdgcn_global_load_lds(
      (const __attribute__((address_space(1))) uint32_t*)g,
      (__attribute__((address_space(3))) uint32_t*)l, 16, 0, 0);
}
__device__ __forceinline__ f32x4 mfma_bf16(bf16x8 a, bf16x8 b, f32x4 c) {
  return __builtin_amdgcn_mfma_f32_16x16x32_bf16(a, b, c, 0, 0, 0);
}

// ---------- kernel 1: x fp32 -> bf16 ----------
__global__ void k_convert_x(const float* __restrict__ x, u16* __restrict__ xb) {
  const int i = (blockIdx.x * 256 + threadIdx.x) * 4;
  float4 v = *(const float4*)(x + i);
  union { u16 h[4]; uint2 v2; } p;
  p.h[0] = f2bf(v.x); p.h[1] = f2bf(v.y); p.h[2] = f2bf(v.z); p.h[3] = f2bf(v.w);
  *(uint2*)(xb + i) = p.v2;
}

// ---------- kernel 2: W[0:512][4096] fp32 -> WxT bf16 [4096][512] ----------
__global__ void k_transpose_wx(const float* __restrict__ W, u16* __restrict__ wxt) {
  __shared__ float tile[64][65];
  const int k0 = blockIdx.x * 64;   // 8 blocks
  const int n0 = blockIdx.y * 64;   // 64 blocks
  const int tn = threadIdx.x & 63, tk = threadIdx.x >> 6;
#pragma unroll
  for (int r = 0; r < 16; r++) {
    const int k = r * 4 + tk;
    tile[k][tn] = W[(size_t)(k0 + k) * NGdim + n0 + tn];
  }
  __syncthreads();
  for (int cid = threadIdx.x; cid < 512; cid += 256) {
    const int nl = cid >> 3, kc = cid & 7;
    union { u16 h[8]; uint4 v; } p;
#pragma unroll
    for (int j = 0; j < 8; j++) p.h[j] = f2bf(tile[kc * 8 + j][nl]);
    *(uint4*)(wxt + (size_t)(n0 + nl) * Ddim + k0 + kc * 8) = p.v;
  }
}

// ---------- kernel 3: XW = x @ Wx + b, permuted output [T][256 g][64 b][16 nl] bf16 ----------
// nl = gate*4 + c ; n_global = gate*1024 + g*4 + c
__global__ __launch_bounds__(256) void k_gemm_xw(
    const u16* __restrict__ xb, const u16* __restrict__ wxt,
    const float* __restrict__ bias, u16* __restrict__ xw)
{
  __shared__ u16 smem[8192];        // 16 KB: sA [kg][128 m][8], sB [kg][128 j][8]
  const int Mtile = blockIdx.x;     // 0..127 (2 t's x 64 b)
  const int Ntile = blockIdx.y;     // 0..31
  const int g0 = Ntile * 8;
  const int tid = threadIdx.x;
  const int lane = tid & 63;
  const int wave = tid >> 6;
  const int wm = wave & 1, wn = wave >> 1;
  const int t0 = Mtile * 2;

  // global row bases (elements): instr pair per wave stages kg = wave
  const size_t a_r0 = ((size_t)lane * Tdim + t0) * Ddim;       // m = lane     (b=lane, t=t0)
  const size_t a_r1 = ((size_t)lane * Tdim + t0 + 1) * Ddim;   // m = 64+lane  (b=lane, t=t0+1)
  const int jc0 = lane, jc1 = 64 + lane;
  const int ng0 = (jc0 >> 5) * 1024 + (g0 + ((jc0 >> 2) & 7)) * 4 + (jc0 & 3);
  const int ng1 = (jc1 >> 5) * 1024 + (g0 + ((jc1 >> 2) & 7)) * 4 + (jc1 & 3);
  const size_t b_r0 = (size_t)ng0 * Ddim;
  const size_t b_r1 = (size_t)ng1 * Ddim;

  u16* sA = smem;
  u16* sB = smem + 4096;
  char* dA0 = (char*)sA + wave * 2048;
  char* dA1 = dA0 + 1024;
  char* dB0 = (char*)sB + wave * 2048;
  char* dB1 = dB0 + 1024;

  f32x4 zero4 = {0.f, 0.f, 0.f, 0.f};
  f32x4 acc[4][4];
#pragma unroll
  for (int i = 0; i < 4; i++)
#pragma unroll
    for (int j = 0; j < 4; j++) acc[i][j] = zero4;

  const int fa = (((lane >> 4) * 128) + wm * 64 + (lane & 15)) * 16;  // byte offsets
  const int fb = (((lane >> 4) * 128) + wn * 64 + (lane & 15)) * 16;

  for (int k0 = 0; k0 < Ddim; k0 += 32) {
    const int koff = k0 + 8 * wave;
    __syncthreads();
    load_lds16(xb + a_r0 + koff, dA0);
    load_lds16(xb + a_r1 + koff, dA1);
    load_lds16(wxt + b_r0 + koff, dB0);
    load_lds16(wxt + b_r1 + koff, dB1);
    __syncthreads();   // compiler inserts vmcnt(0) before barrier
    bf16x8 af[4], bfr[4];
#pragma unroll
    for (int i = 0; i < 4; i++) {
      af[i]  = *(const bf16x8*)((const char*)sA + fa + i * 256);
      bfr[i] = *(const bf16x8*)((const char*)sB + fb + i * 256);
    }
#pragma unroll
    for (int mt = 0; mt < 4; mt++)
#pragma unroll
      for (int nt = 0; nt < 4; nt++)
        acc[mt][nt] = mfma_bf16(af[mt], bfr[nt], acc[mt][nt]);
  }

  // epilogue: LDS bounce per t-half, coalesced permuted stores
#pragma unroll 1
  for (int th = 0; th < 2; th++) {
    __syncthreads();
    if (wm == th) {
      const int q = lane >> 4, col0 = wn * 64 + (lane & 15);
#pragma unroll
      for (int mt = 0; mt < 4; mt++)
#pragma unroll
        for (int nt = 0; nt < 4; nt++)
#pragma unroll
          for (int i = 0; i < 4; i++)
            smem[(mt * 16 + q * 4 + i) * 128 + col0 + nt * 16] = f2bf(acc[mt][nt][i]);
    }
    __syncthreads();
    const int t = t0 + th;
    for (int cid = tid; cid < 512; cid += 256) {
      const int gsub = cid >> 6;
      const int b = cid & 63;
      union { u16 h[16]; uint4 v[2]; } pack;
#pragma unroll
      for (int gate = 0; gate < 4; gate++)
#pragma unroll
        for (int c = 0; c < 4; c++) {
          float v = bf2f(smem[b * 128 + gate * 32 + gsub * 4 + c])
                  + bias[gate * 1024 + (g0 + gsub) * 4 + c];
          pack.h[gate * 4 + c] = f2bf(v);
        }
      uint4* dst = (uint4*)(xw + ((((size_t)t * 256) + g0 + gsub) * 64 + b) * 16);
      dst[0] = pack.v[0];
      dst[1] = pack.v[1];
    }
  }
}

// ---------- kernel 4: persistent cooperative LSTM recurrence ----------
// 256 WGs x 256 thr. WG gid owns h-cols [gid*4, gid*4+4) across all 4 gates.
// W_h slice resident in LDS (bf16, [kg 128][nl 16][8]); h double-buffered bf16 in ws.
__global__ __launch_bounds__(256) void k_lstm(
    const float* __restrict__ W, const u16* __restrict__ xw,
    const int* __restrict__ seq_len, u16* __restrict__ hbuf,
    float* __restrict__ out)
{
  __shared__ u16 wlds[128 * 16 * 8];   // 32 KB
  __shared__ float zlds[64 * 17];      // padded
  const int gid = blockIdx.x;          // 0..255
  const int tid = threadIdx.x;
  const int lane = tid & 63;
  const int wave = tid >> 6;           // m-tile (batch rows wave*16..wave*16+15)

  { // one-time W_h slice load -> LDS bf16
    const int gate = tid & 3;
    const int kb = tid >> 2;           // 0..63
    const int ngc = gate * 1024 + gid * 4;
#pragma unroll 1
    for (int kk = 0; kk < 16; kk++) {
      const int k = kb * 16 + kk;
      const float4 wv = *(const float4*)(W + (size_t)(Ddim + k) * NGdim + ngc);
      const int base = ((k >> 3) * 16 + gate * 4) * 8 + (k & 7);
      wlds[base]      = f2bf(wv.x);
      wlds[base + 8]  = f2bf(wv.y);
      wlds[base + 16] = f2bf(wv.z);
      wlds[base + 24] = f2bf(wv.w);
    }
  }
  const int b_t = tid >> 2, c_t = tid & 3;
  hbuf[(size_t)b_t * Hdim + gid * 4 + c_t] = 0;   // zero h_buf[0] slice (ws is poisoned)
  float c_reg = 0.f, h_reg = 0.f;
  const int slen = seq_len[b_t];

  cg::grid_group grid = cg::this_grid();
  grid.sync();

  const int fb = ((lane >> 4) * 16 + (lane & 15)) * 8;                 // wlds elem offset (+kt*512)
  const size_t a0 = ((size_t)(wave * 16 + (lane & 15)) * Hdim) + (lane >> 4) * 8;
  const int q = lane >> 4, col = lane & 15;
  const f32x4 zero4 = {0.f, 0.f, 0.f, 0.f};

  for (int t = 0; t < Tdim; t++) {
    const u16* hsrc = hbuf + (size_t)(t & 1) * (Bdim * Hdim);
    u16* hdst = hbuf + (size_t)((t + 1) & 1) * (Bdim * Hdim);
    f32x4 acc0 = zero4, acc1 = zero4;
#pragma unroll 4
    for (int kt = 0; kt < 32; kt += 2) {
      bf16x8 av0 = *(const bf16x8*)(hsrc + a0 + (size_t)kt * 32);
      bf16x8 bv0 = *(const bf16x8*)(wlds + kt * 512 + fb);
      acc0 = mfma_bf16(av0, bv0, acc0);
      bf16x8 av1 = *(const bf16x8*)(hsrc + a0 + (size_t)kt * 32 + 32);
      bf16x8 bv1 = *(const bf16x8*)(wlds + (kt + 1) * 512 + fb);
      acc1 = mfma_bf16(av1, bv1, acc1);
    }
    { // z tile -> LDS
      const int r0 = wave * 16 + q * 4;
#pragma unroll
      for (int i = 0; i < 4; i++)
        zlds[(r0 + i) * 17 + col] = acc0[i] + acc1[i];
    }
    __syncthreads();
    { // gates + state update: thread owns (batch b_t, h-col gid*4+c_t)
      const u16* xwp = xw + ((((size_t)t * 256) + gid) * 64 + b_t) * 16;
      float zi = zlds[b_t * 17 + 0  + c_t] + bf2f(xwp[0  + c_t]);
      float zj = zlds[b_t * 17 + 4  + c_t] + bf2f(xwp[4  + c_t]);
      float zf = zlds[b_t * 17 + 8  + c_t] + bf2f(xwp[8  + c_t]);
      float zo = zlds[b_t * 17 + 12 + c_t] + bf2f(xwp[12 + c_t]);
      if (t < slen) {
        c_reg = c_reg * sigm(zf + 1.0f) + sigm(zi) * tanh_fast(zj);
        h_reg = tanh_fast(c_reg) * sigm(zo);
      }
      hdst[(size_t)b_t * Hdim + gid * 4 + c_t] = f2bf(h_reg);
    }
    grid.sync();
  }
  out[(size_t)b_t * Hdim + gid * 4 + c_t] = h_reg;
}

// ---------- host ----------
extern "C" void kernel_launch(void* const* d_in, const int* in_sizes, int n_in,
                              void* d_out, int out_size, void* d_ws, size_t ws_size,
                              hipStream_t stream) {
  (void)in_sizes; (void)n_in; (void)out_size; (void)ws_size;
  const float* x       = (const float*)d_in[0];
  const int*   seq_len = (const int*)d_in[1];
  const float* W       = (const float*)d_in[2];
  const float* bias    = (const float*)d_in[3];
  float* out = (float*)d_out;

  char* ws = (char*)d_ws;
  u16* xw   = (u16*)(ws);                                              // 128 MB  [T][256][64][16] bf16
  u16* xb   = (u16*)(ws + (size_t)134217728);                          // 16 MB   x bf16 [B][T][D]
  u16* wxt  = (u16*)(ws + (size_t)134217728 + 16777216);               // 4 MB    WxT bf16 [4096][512]
  u16* hbuf = (u16*)(ws + (size_t)134217728 + 16777216 + 4194304);     // 256 KB  h double buffer

  k_convert_x<<<dim3(8192), dim3(256), 0, stream>>>(x, xb);
  k_transpose_wx<<<dim3(8, 64), dim3(256), 0, stream>>>(W, wxt);
  k_gemm_xw<<<dim3(128, 32), dim3(256), 0, stream>>>(xb, wxt, bias, xw);

  void* args[5];
  args[0] = (void*)&W;
  args[1] = (void*)&xw;
  args[2] = (void*)&seq_len;
  args[3] = (void*)&hbuf;
  args[4] = (void*)&out;
  hipLaunchCooperativeKernel((const void*)k_lstm, dim3(256), dim3(256), args, 0, stream);
}

// Round 6
// 2346.144 us; speedup vs baseline: 4.1200x; 4.1200x over previous
//
#include <hip/hip_runtime.h>
#include <stdint.h>

typedef unsigned short u16;
typedef __bf16 bf16_t;
typedef bf16_t bf16x8 __attribute__((ext_vector_type(8)));
typedef float f32x4 __attribute__((ext_vector_type(4)));

#define Bdim 64
#define Tdim 256
#define Ddim 512
#define Hdim 1024
#define NGdim 4096

// ---------- helpers ----------
__device__ __forceinline__ u16 f2bf(float f) {
  union { float f; uint32_t u; } v; v.f = f;
  return (u16)((v.u + 0x7FFFu + ((v.u >> 16) & 1u)) >> 16);   // RNE
}
__device__ __forceinline__ float bf2f(u16 h) {
  union { uint32_t u; float f; } v; v.u = ((uint32_t)h) << 16;
  return v.f;
}
__device__ __forceinline__ float sigm(float x) { return 1.0f / (1.0f + __expf(-x)); }
__device__ __forceinline__ float tanh_fast(float x) { return 2.0f / (1.0f + __expf(-2.0f * x)) - 1.0f; }

__device__ __forceinline__ void load_lds16(const void* g, void* l) {
  __builtin_amdgcn_global_load_lds(
      (const __attribute__((address_space(1))) uint32_t*)g,
      (__attribute__((address_space(3))) uint32_t*)l, 16, 0, 0);
}
__device__ __forceinline__ f32x4 mfma_bf16(bf16x8 a, bf16x8 b, f32x4 c) {
  return __builtin_amdgcn_mfma_f32_16x16x32_bf16(a, b, c, 0, 0, 0);
}

// ---------- kernel 0: zero h double-buffer (bf16) + c buffer (fp32) ----------
__global__ void k_init(uint64_t* __restrict__ zreg) {
  zreg[blockIdx.x * 256 + threadIdx.x] = 0ull;   // 256 WGs x 256 x 8 B = 512 KB
}

// ---------- kernel 1: x fp32 -> bf16 ----------
__global__ void k_convert_x(const float* __restrict__ x, u16* __restrict__ xb) {
  const int i = (blockIdx.x * 256 + threadIdx.x) * 4;
  float4 v = *(const float4*)(x + i);
  union { u16 h[4]; uint2 v2; } p;
  p.h[0] = f2bf(v.x); p.h[1] = f2bf(v.y); p.h[2] = f2bf(v.z); p.h[3] = f2bf(v.w);
  *(uint2*)(xb + i) = p.v2;
}

// ---------- kernel 2: W[0:512][4096] fp32 -> WxT bf16 [4096][512] ----------
__global__ void k_transpose_wx(const float* __restrict__ W, u16* __restrict__ wxt) {
  __shared__ float tile[64][65];
  const int k0 = blockIdx.x * 64;   // 8 blocks
  const int n0 = blockIdx.y * 64;   // 64 blocks
  const int tn = threadIdx.x & 63, tk = threadIdx.x >> 6;
#pragma unroll
  for (int r = 0; r < 16; r++) {
    const int k = r * 4 + tk;
    tile[k][tn] = W[(size_t)(k0 + k) * NGdim + n0 + tn];
  }
  __syncthreads();
  for (int cid = threadIdx.x; cid < 512; cid += 256) {
    const int nl = cid >> 3, kc = cid & 7;
    union { u16 h[8]; uint4 v; } p;
#pragma unroll
    for (int j = 0; j < 8; j++) p.h[j] = f2bf(tile[kc * 8 + j][nl]);
    *(uint4*)(wxt + (size_t)(n0 + nl) * Ddim + k0 + kc * 8) = p.v;
  }
}

// ---------- kernel 3: W_h -> per-WG fragment layout whT[gid][kt4][16 nl][8 kk] bf16 (8 MB) ----------
// Same layout as round-1's verified wlds staging, but written to global once.
__global__ void k_prep_wh(const float* __restrict__ W, u16* __restrict__ whT) {
  const int gid = blockIdx.x;          // 0..255
  u16* dst = whT + (size_t)gid * 16384;
  const int gate = threadIdx.x & 3;
  const int kb = threadIdx.x >> 2;     // 0..63
  const int ngc = gate * 1024 + gid * 4;
#pragma unroll 1
  for (int kk = 0; kk < 16; kk++) {
    const int k = kb * 16 + kk;
    const float4 wv = *(const float4*)(W + (size_t)(Ddim + k) * NGdim + ngc);
    const int base = ((k >> 3) * 16 + gate * 4) * 8 + (k & 7);
    dst[base]      = f2bf(wv.x);
    dst[base + 8]  = f2bf(wv.y);
    dst[base + 16] = f2bf(wv.z);
    dst[base + 24] = f2bf(wv.w);
  }
}

// ---------- kernel 4: XW = x @ Wx + b, permuted output [T][256 g][64 b][16 nl] bf16 ----------
__global__ __launch_bounds__(256) void k_gemm_xw(
    const u16* __restrict__ xb, const u16* __restrict__ wxt,
    const float* __restrict__ bias, u16* __restrict__ xw)
{
  __shared__ u16 smem[8192];        // 16 KB: sA [kg][128 m][8], sB [kg][128 j][8]
  const int Mtile = blockIdx.x;     // 0..127 (2 t's x 64 b)
  const int Ntile = blockIdx.y;     // 0..31
  const int g0 = Ntile * 8;
  const int tid = threadIdx.x;
  const int lane = tid & 63;
  const int wave = tid >> 6;
  const int wm = wave & 1, wn = wave >> 1;
  const int t0 = Mtile * 2;

  const size_t a_r0 = ((size_t)lane * Tdim + t0) * Ddim;
  const size_t a_r1 = ((size_t)lane * Tdim + t0 + 1) * Ddim;
  const int jc0 = lane, jc1 = 64 + lane;
  const int ng0 = (jc0 >> 5) * 1024 + (g0 + ((jc0 >> 2) & 7)) * 4 + (jc0 & 3);
  const int ng1 = (jc1 >> 5) * 1024 + (g0 + ((jc1 >> 2) & 7)) * 4 + (jc1 & 3);
  const size_t b_r0 = (size_t)ng0 * Ddim;
  const size_t b_r1 = (size_t)ng1 * Ddim;

  u16* sA = smem;
  u16* sB = smem + 4096;
  char* dA0 = (char*)sA + wave * 2048;
  char* dA1 = dA0 + 1024;
  char* dB0 = (char*)sB + wave * 2048;
  char* dB1 = dB0 + 1024;

  f32x4 zero4 = {0.f, 0.f, 0.f, 0.f};
  f32x4 acc[4][4];
#pragma unroll
  for (int i = 0; i < 4; i++)
#pragma unroll
    for (int j = 0; j < 4; j++) acc[i][j] = zero4;

  const int fa = (((lane >> 4) * 128) + wm * 64 + (lane & 15)) * 16;
  const int fb = (((lane >> 4) * 128) + wn * 64 + (lane & 15)) * 16;

  for (int k0 = 0; k0 < Ddim; k0 += 32) {
    const int koff = k0 + 8 * wave;
    __syncthreads();
    load_lds16(xb + a_r0 + koff, dA0);
    load_lds16(xb + a_r1 + koff, dA1);
    load_lds16(wxt + b_r0 + koff, dB0);
    load_lds16(wxt + b_r1 + koff, dB1);
    __syncthreads();
    bf16x8 af[4], bfr[4];
#pragma unroll
    for (int i = 0; i < 4; i++) {
      af[i]  = *(const bf16x8*)((const char*)sA + fa + i * 256);
      bfr[i] = *(const bf16x8*)((const char*)sB + fb + i * 256);
    }
#pragma unroll
    for (int mt = 0; mt < 4; mt++)
#pragma unroll
      for (int nt = 0; nt < 4; nt++)
        acc[mt][nt] = mfma_bf16(af[mt], bfr[nt], acc[mt][nt]);
  }

#pragma unroll 1
  for (int th = 0; th < 2; th++) {
    __syncthreads();
    if (wm == th) {
      const int q = lane >> 4, col0 = wn * 64 + (lane & 15);
#pragma unroll
      for (int mt = 0; mt < 4; mt++)
#pragma unroll
        for (int nt = 0; nt < 4; nt++)
#pragma unroll
          for (int i = 0; i < 4; i++)
            smem[(mt * 16 + q * 4 + i) * 128 + col0 + nt * 16] = f2bf(acc[mt][nt][i]);
    }
    __syncthreads();
    const int t = t0 + th;
    for (int cid = tid; cid < 512; cid += 256) {
      const int gsub = cid >> 6;
      const int b = cid & 63;
      union { u16 h[16]; uint4 v[2]; } pack;
#pragma unroll
      for (int gate = 0; gate < 4; gate++)
#pragma unroll
        for (int c = 0; c < 4; c++) {
          float v = bf2f(smem[b * 128 + gate * 32 + gsub * 4 + c])
                  + bias[gate * 1024 + (g0 + gsub) * 4 + c];
          pack.h[gate * 4 + c] = f2bf(v);
        }
      uint4* dst = (uint4*)(xw + ((((size_t)t * 256) + g0 + gsub) * 64 + b) * 16);
      dst[0] = pack.v[0];
      dst[1] = pack.v[1];
    }
  }
}

// ---------- kernel 5: one LSTM timestep (launched 256x; kernel boundary = sync) ----------
// WG gid computes the 64x16 z-tile for h-cols [gid*4,gid*4+4) x 4 gates, then the
// owning thread updates (c,h) for (batch b_t, col gid*4+c_t). Round-1 verified dataflow;
// c carried in global fp32, h double-buffered bf16. No intra-kernel cross-WG sync.
__global__ __launch_bounds__(256) void k_step(
    const u16* __restrict__ whT, const u16* __restrict__ xw,
    const int* __restrict__ seq_len,
    const u16* __restrict__ hsrc, u16* __restrict__ hdst,
    float* __restrict__ cbuf, float* __restrict__ out, int t)
{
  __shared__ float zlds[64 * 17];
  const int gid = blockIdx.x;          // 0..255
  const int tid = threadIdx.x;
  const int lane = tid & 63;
  const int wave = tid >> 6;           // batch rows wave*16..wave*16+15

  // B fragments: coalesced from the pre-permuted whT slice (same mapping as round-1 wlds)
  const u16* wp = whT + (size_t)gid * 16384 + ((lane >> 4) * 16 + (lane & 15)) * 8;
  // A fragments: h rows (verified round-1 mapping)
  const u16* pA = hsrc + ((size_t)(wave * 16 + (lane & 15)) * Hdim) + (lane >> 4) * 8;

  const f32x4 zero4 = {0.f, 0.f, 0.f, 0.f};
  f32x4 acc[4] = {zero4, zero4, zero4, zero4};
#pragma unroll
  for (int kt = 0; kt < 32; kt++)
    acc[kt & 3] = mfma_bf16(*(const bf16x8*)(pA + kt * 32),
                            *(const bf16x8*)(wp + kt * 512), acc[kt & 3]);

  { // z tile -> LDS (C/D layout: col=lane&15, row=(lane>>4)*4+i)
    const int q = lane >> 4, col = lane & 15;
    const int r0 = wave * 16 + q * 4;
#pragma unroll
    for (int i = 0; i < 4; i++)
      zlds[(r0 + i) * 17 + col] = acc[0][i] + acc[1][i] + acc[2][i] + acc[3][i];
  }
  __syncthreads();

  // gates + state update: thread owns (batch b_t, h-col gid*4+c_t)
  const int b_t = tid >> 2, c_t = tid & 3;
  const u16* xwp = xw + ((((size_t)t * 256) + gid) * 64 + b_t) * 16 + c_t;
  const float zi = zlds[b_t * 17 + 0  + c_t] + bf2f(xwp[0]);
  const float zj = zlds[b_t * 17 + 4  + c_t] + bf2f(xwp[4]);
  const float zf = zlds[b_t * 17 + 8  + c_t] + bf2f(xwp[8]);
  const float zo = zlds[b_t * 17 + 12 + c_t] + bf2f(xwp[12]);

  const int hidx = b_t * Hdim + gid * 4 + c_t;
  const float c_old = cbuf[hidx];
  float nc = c_old, nh = bf2f(hsrc[hidx]);
  if (t < seq_len[b_t]) {
    nc = c_old * sigm(zf + 1.0f) + sigm(zi) * tanh_fast(zj);
    nh = tanh_fast(nc) * sigm(zo);
  }
  cbuf[hidx] = nc;
  hdst[hidx] = f2bf(nh);
  if (t == Tdim - 1) out[hidx] = nh;
}

// ---------- host ----------
extern "C" void kernel_launch(void* const* d_in, const int* in_sizes, int n_in,
                              void* d_out, int out_size, void* d_ws, size_t ws_size,
                              hipStream_t stream) {
  (void)in_sizes; (void)n_in; (void)out_size; (void)ws_size;
  const float* x       = (const float*)d_in[0];
  const int*   seq_len = (const int*)d_in[1];
  const float* W       = (const float*)d_in[2];
  const float* bias    = (const float*)d_in[3];
  float* out = (float*)d_out;

  char* ws = (char*)d_ws;
  u16*   xw   = (u16*)(ws);                                  // 128 MB [T][256][64][16] bf16
  u16*   xb   = (u16*)(ws + (size_t)134217728);              // 16 MB  x bf16 [B][T][D]
  u16*   wxt  = (u16*)(ws + (size_t)150994944);              // 4 MB   WxT bf16 [4096][512]
  u16*   whT  = (u16*)(ws + (size_t)155189248);              // 8 MB   W_h fragments [256][16384]
  char*  hreg = ws + (size_t)163577856;                      // 256 KB h dbuf + 256 KB c fp32
  u16*   hbuf = (u16*)hreg;
  float* cbuf = (float*)(hreg + 262144);

  k_init<<<dim3(256), dim3(256), 0, stream>>>((uint64_t*)hreg);          // zero h+c (512 KB)
  k_convert_x<<<dim3(8192), dim3(256), 0, stream>>>(x, xb);
  k_transpose_wx<<<dim3(8, 64), dim3(256), 0, stream>>>(W, wxt);
  k_prep_wh<<<dim3(256), dim3(256), 0, stream>>>(W, whT);
  k_gemm_xw<<<dim3(128, 32), dim3(256), 0, stream>>>(xb, wxt, bias, xw);

  for (int t = 0; t < Tdim; t++) {
    const u16* hs = hbuf + (size_t)(t & 1) * (Bdim * Hdim);
    u16* hd = hbuf + (size_t)((t + 1) & 1) * (Bdim * Hdim);
    k_step<<<dim3(256), dim3(256), 0, stream>>>(whT, xw, seq_len, hs, hd, cbuf, out, t);
  }
}